// Round 5
// baseline (78.366 us; speedup 1.0000x reference)
//
#include <hip/hip_runtime.h>
#include <stdint.h>

#define NF   2344
#define ACCW 8
#define NA   38
#define TPB  1024

__device__ __forceinline__ unsigned short f32_to_bf16(float f) {
    unsigned u = __float_as_uint(f);
    u += 0x7FFFu + ((u >> 16) & 1u);   // round-to-nearest-even
    return (unsigned short)(u >> 16);
}
__device__ __forceinline__ float bf16_lo(unsigned u) { return __uint_as_float(u << 16); }
__device__ __forceinline__ float bf16_hi(unsigned u) { return __uint_as_float(u & 0xFFFF0000u); }

// 2 threads per element (h = t&1). Each lane loads HALF the int2-slots of BOTH
// colors, arranged so a lane-pair's loads are 16B-contiguous per instruction
// (halves the L1 line-events of the index stream vs per-color strided loads).
// Pair-reduce partial accumulators via shfl_xor at the end.
__global__ __launch_bounds__(TPB, 8) void nnue_fwd(
    const int* __restrict__ bfeat, const int* __restrict__ wfeat,
    const int* __restrict__ stm,
    const float* __restrict__ w1, const float* __restrict__ b1,
    const float* __restrict__ w2, const float* __restrict__ b2,
    float* __restrict__ out, int nbatch)
{
    __shared__ unsigned short tbl[NF * ACCW];   // bf16 table, 16B per row (37.9 KB)

    for (int j = threadIdx.x; j < (NF * ACCW) / 4; j += TPB) {
        float4 v = reinterpret_cast<const float4*>(w1)[j];
        unsigned lo = (unsigned)f32_to_bf16(v.x) | ((unsigned)f32_to_bf16(v.y) << 16);
        unsigned hi = (unsigned)f32_to_bf16(v.z) | ((unsigned)f32_to_bf16(v.w) << 16);
        reinterpret_cast<uint2*>(tbl)[j] = make_uint2(lo, hi);
    }
    __syncthreads();

    const int t = blockIdx.x * TPB + threadIdx.x;
    const int e = t >> 1;
    const int h = t & 1;
    if (e >= nbatch) return;

    const int* __restrict__ bp = bfeat + (long)e * NA;
    const int* __restrict__ wp = wfeat + (long)e * NA;

#define G(acc, idx) { \
        uint4 r = *reinterpret_cast<const uint4*>( \
            reinterpret_cast<const char*>(tbl) + ((unsigned)(idx) << 4)); \
        acc[0] += bf16_lo(r.x); acc[1] += bf16_hi(r.x); \
        acc[2] += bf16_lo(r.y); acc[3] += bf16_hi(r.y); \
        acc[4] += bf16_lo(r.z); acc[5] += bf16_hi(r.z); \
        acc[6] += bf16_lo(r.w); acc[7] += bf16_hi(r.w); }

    float accB[8] = {0,0,0,0,0,0,0,0};
    float accW[8] = {0,0,0,0,0,0,0,0};

    // ---- black: lane h takes slots {2j+h}; pair covers contiguous 16B ----
    {
        int2 q[10];
#pragma unroll
        for (int j = 0; j < 9; ++j)
            q[j] = *reinterpret_cast<const int2*>(bp + 4 * j + 2 * h);
        if (h == 0) q[9] = *reinterpret_cast<const int2*>(bp + 36);
#pragma unroll
        for (int j = 0; j < 9; ++j) { G(accB, q[j].x); G(accB, q[j].y); }
        if (h == 0) { G(accB, q[9].x); G(accB, q[9].y); }
    }

    // ---- white: lane h takes slots {2j+(1-h)} ----
    {
        int2 q[10];
#pragma unroll
        for (int j = 0; j < 9; ++j)
            q[j] = *reinterpret_cast<const int2*>(wp + 4 * j + 2 * (1 - h));
        if (h == 1) q[9] = *reinterpret_cast<const int2*>(wp + 36);
#pragma unroll
        for (int j = 0; j < 9; ++j) { G(accW, q[j].x); G(accW, q[j].y); }
        if (h == 1) { G(accW, q[9].x); G(accW, q[9].y); }
    }
#undef G

    // ---- pair-reduce partials; lane h finalizes color h (0=black,1=white) ----
    float mine[8];
#pragma unroll
    for (int k = 0; k < 8; ++k) {
        float fb = accB[k] + __shfl_xor(accB[k], 1);
        float fw = accW[k] + __shfl_xor(accW[k], 1);
        mine[k] = (h ? fw : fb) + b1[k];
    }

    float dlo = 0.f, dhi = 0.f;
#pragma unroll
    for (int k = 0; k < 8; ++k) {
        float v = fminf(fmaxf(mine[k], 0.f), 1.f);
        dlo += v * w2[k];
        dhi += v * w2[8 + k];
    }

    // stm==0 -> order [black, white]; black half of w2 is [0:8].
    const int s = stm[e];
    const float m = (((s == 0)) == (h == 0)) ? dlo : dhi;
    const float o = __shfl_xor(m, 1);
    if (h == 0) out[e] = m + o + b2[0];
}

extern "C" void kernel_launch(void* const* d_in, const int* in_sizes, int n_in,
                              void* d_out, int out_size, void* d_ws, size_t ws_size,
                              hipStream_t stream) {
    const int*   bfeat = (const int*)  d_in[0];
    const int*   wfeat = (const int*)  d_in[1];
    const int*   stm   = (const int*)  d_in[2];
    const float* w1    = (const float*)d_in[3];
    const float* b1    = (const float*)d_in[4];
    const float* w2    = (const float*)d_in[5];
    const float* b2    = (const float*)d_in[6];
    float* out = (float*)d_out;

    const int nbatch  = in_sizes[2];
    const long nthread = (long)nbatch * 2;
    const int grid = (int)((nthread + TPB - 1) / TPB);
    nnue_fwd<<<grid, TPB, 0, stream>>>(bfeat, wfeat, stm, w1, b1, w2, b2, out, nbatch);
}

// Round 6
// 21.955 us; speedup vs baseline: 3.5695x; 3.5695x over previous
//
#include <hip/hip_runtime.h>
#include <stdint.h>

#define NF   2344
#define ACCW 8
#define NA   38
#define TPB  512

__device__ __forceinline__ unsigned short f32_to_bf16(float f) {
    unsigned u = __float_as_uint(f);
    u += 0x7FFFu + ((u >> 16) & 1u);   // round-to-nearest-even
    return (unsigned short)(u >> 16);
}
__device__ __forceinline__ float bf16_lo(unsigned u) { return __uint_as_float(u << 16); }
__device__ __forceinline__ float bf16_hi(unsigned u) { return __uint_as_float(u & 0xFFFF0000u); }

// 2 threads per element (h = t&1). Lane h loads int2-slots {2j+h} of each
// color's 19-slot index row, so each lane-pair's load instr covers one
// contiguous 16B window (halves L1 line-events). Slot 18 is loaded by both
// lanes (same addr) and split .x/.y between them -> 38 full-exec gathers,
// no divergent tail. Pair-reduce partial accumulators via shfl_xor.
__global__ __launch_bounds__(TPB, 4) void nnue_fwd(
    const int* __restrict__ bfeat, const int* __restrict__ wfeat,
    const int* __restrict__ stm,
    const float* __restrict__ w1, const float* __restrict__ b1,
    const float* __restrict__ w2, const float* __restrict__ b2,
    float* __restrict__ out, int nbatch)
{
    __shared__ unsigned short tbl[NF * ACCW];   // bf16 table, 16B/row (37.9 KB)

    for (int j = threadIdx.x; j < (NF * ACCW) / 4; j += TPB) {
        float4 v = reinterpret_cast<const float4*>(w1)[j];
        unsigned lo = (unsigned)f32_to_bf16(v.x) | ((unsigned)f32_to_bf16(v.y) << 16);
        unsigned hi = (unsigned)f32_to_bf16(v.z) | ((unsigned)f32_to_bf16(v.w) << 16);
        reinterpret_cast<uint2*>(tbl)[j] = make_uint2(lo, hi);
    }
    __syncthreads();

    const int t = blockIdx.x * TPB + threadIdx.x;
    const int e = t >> 1;
    const int h = t & 1;
    if (e >= nbatch) return;

    const int* __restrict__ bp = bfeat + (long)e * NA;
    const int* __restrict__ wp = wfeat + (long)e * NA;

#define G(acc, idx) { \
        uint4 r = *reinterpret_cast<const uint4*>( \
            reinterpret_cast<const char*>(tbl) + ((unsigned)(idx) << 4)); \
        acc[0] += bf16_lo(r.x); acc[1] += bf16_hi(r.x); \
        acc[2] += bf16_lo(r.y); acc[3] += bf16_hi(r.y); \
        acc[4] += bf16_lo(r.z); acc[5] += bf16_hi(r.z); \
        acc[6] += bf16_lo(r.w); acc[7] += bf16_hi(r.w); }

    float accB[8] = {0,0,0,0,0,0,0,0};
    float accW[8] = {0,0,0,0,0,0,0,0};

    // ---- black ----
    {
        int2 q[9];
#pragma unroll
        for (int j = 0; j < 9; ++j)
            q[j] = *reinterpret_cast<const int2*>(bp + 4 * j + 2 * h);
        const int2 qt = *reinterpret_cast<const int2*>(bp + 36);  // shared slot
#pragma unroll
        for (int j = 0; j < 9; ++j) { G(accB, q[j].x); G(accB, q[j].y); }
        G(accB, h ? qt.y : qt.x);
    }

    asm volatile("" ::: "memory");   // don't hoist white loads over black gathers

    // ---- white ----
    {
        int2 q[9];
#pragma unroll
        for (int j = 0; j < 9; ++j)
            q[j] = *reinterpret_cast<const int2*>(wp + 4 * j + 2 * h);
        const int2 qt = *reinterpret_cast<const int2*>(wp + 36);
#pragma unroll
        for (int j = 0; j < 9; ++j) { G(accW, q[j].x); G(accW, q[j].y); }
        G(accW, h ? qt.y : qt.x);
    }
#undef G

    // ---- pair-reduce partials; lane h finalizes color h (0=black,1=white) ----
    float mine[8];
#pragma unroll
    for (int k = 0; k < 8; ++k) {
        float fb = accB[k] + __shfl_xor(accB[k], 1);
        float fw = accW[k] + __shfl_xor(accW[k], 1);
        mine[k] = (h ? fw : fb) + b1[k];
    }

    float dlo = 0.f, dhi = 0.f;
#pragma unroll
    for (int k = 0; k < 8; ++k) {
        float v = fminf(fmaxf(mine[k], 0.f), 1.f);
        dlo += v * w2[k];
        dhi += v * w2[8 + k];
    }

    // stm==0 -> order [black, white]; black half of w2 is [0:8].
    const int s = stm[e];
    const float m = (((s == 0)) == (h == 0)) ? dlo : dhi;
    const float o = __shfl_xor(m, 1);
    if (h == 0) out[e] = m + o + b2[0];
}

extern "C" void kernel_launch(void* const* d_in, const int* in_sizes, int n_in,
                              void* d_out, int out_size, void* d_ws, size_t ws_size,
                              hipStream_t stream) {
    const int*   bfeat = (const int*)  d_in[0];
    const int*   wfeat = (const int*)  d_in[1];
    const int*   stm   = (const int*)  d_in[2];
    const float* w1    = (const float*)d_in[3];
    const float* b1    = (const float*)d_in[4];
    const float* w2    = (const float*)d_in[5];
    const float* b2    = (const float*)d_in[6];
    float* out = (float*)d_out;

    const int nbatch  = in_sizes[2];
    const long nthread = (long)nbatch * 2;
    const int grid = (int)((nthread + TPB - 1) / TPB);
    nnue_fwd<<<grid, TPB, 0, stream>>>(bfeat, wfeat, stm, w1, b1, w2, b2, out, nbatch);
}